// Round 3
// baseline (148.724 us; speedup 1.0000x reference)
//
#include <hip/hip_runtime.h>
#include <math.h>

// ---------------------------------------------------------------------------
// TwoSimplicialAttention, MI355X. Structure exploit: mask kills attention for
// all s < 2016; only last 32 rows/batch (64 rows) carry attention. Everything
// else is out = LayerNorm(x).
//
// R3: no zero_ws/atomics (split-k partial buffers, plain stores);
// attn: swizzled Kn/Kp (conflict-free QK b128), float4 P matrix (pad 36).
// ---------------------------------------------------------------------------

#define XS 68   // Vs pad

// workspace layout (floats)
#define NSPLIT    8
#define YPART_SZ  262144            // 64 x 4096 per split part
#define Z_OFF     (NSPLIT * YPART_SZ)          // 2097152: 64 x 1024
#define DPART_OFF (Z_OFF + 65536)              // 2162688: 8 x 64 x 1024
// total 2686976 floats = 10.75 MB (< ws)

// Y sub-offsets inside one part: z*65536, z in {Q=0,K=1,Kp=2,V=3}

__device__ __forceinline__ int sw_idx(int row, int d) {
  // swizzled LDS index for 32x64 tiles read as float4 along d by row-groups
  return row * 64 + ((((d >> 2) + (row >> 2)) & 15) << 2) + (d & 3);
}

// ---- kernel A: Ypart[ks][64][4096] = x_win @ [W_Q|W_K|W_Kp|W_V] (k-chunk) -
// grid (64 = 4 z * 16 colblk, 8 ksplit). lane=row, wave owns 16 cols,
// W rows via scalar cache (s_load_dwordx16), plain coalesced stores.
__global__ __launch_bounds__(256, 2) void proj_kernel(
    const float* __restrict__ x,
    const float* __restrict__ Wq, const float* __restrict__ Wk,
    const float* __restrict__ Wkp, const float* __restrict__ Wv,
    float* __restrict__ ws) {
  __shared__ float xs[128 * 65];     // [kk][r]
  const int tid = threadIdx.x;
  const int z    = blockIdx.x >> 4;
  const int col0 = (blockIdx.x & 15) * 64;
  const int ks   = blockIdx.y;
  const int k0   = ks * 128;
  const float* __restrict__ W =
      (z == 0) ? Wq : ((z == 1) ? Wk : ((z == 2) ? Wkp : Wv));

  // stage x^T tile: 64 rows x 128 k (coalesced float4)
  #pragma unroll
  for (int i = 0; i < 8; i++) {
    int e = i * 256 + tid;           // 2048 slots: r(64) x quad(32)
    int r = e >> 5, q = e & 31;
    int b = r >> 5, t = r & 31;
    float4 v = *(const float4*)(x + ((b * 2048 + 2016 + t) * 1024 + k0 + q * 4));
    xs[(q * 4 + 0) * 65 + r] = v.x;
    xs[(q * 4 + 1) * 65 + r] = v.y;
    xs[(q * 4 + 2) * 65 + r] = v.z;
    xs[(q * 4 + 3) * 65 + r] = v.w;
  }
  __syncthreads();

  const int wave = __builtin_amdgcn_readfirstlane(tid >> 6);  // uniform
  const int lane = tid & 63;                                   // = row
  const float* __restrict__ Wt = W + (size_t)k0 * 1024 + col0 + wave * 16;

  float acc[16];
  #pragma unroll
  for (int c = 0; c < 16; c++) acc[c] = 0.f;

  #pragma unroll 4
  for (int kk = 0; kk < 128; kk++) {
    float xv = xs[kk * 65 + lane];               // conflict-free vector read
    const float* __restrict__ wrow = Wt + kk * 1024;  // uniform -> s_load x16
    #pragma unroll
    for (int c = 0; c < 16; c++) acc[c] = fmaf(xv, wrow[c], acc[c]);
  }

  // transpose through LDS for coalesced stores
  __syncthreads();
  #pragma unroll
  for (int c = 0; c < 16; c++) xs[lane * 65 + wave * 16 + c] = acc[c];
  __syncthreads();
  float* __restrict__ Yo = ws + (size_t)ks * YPART_SZ + z * 65536 + col0;
  #pragma unroll
  for (int i = 0; i < 16; i++) {
    int r = wave * 16 + i;
    Yo[r * 1024 + lane] = xs[r * 65 + lane];     // 64 lanes coalesced
  }
}

// ---- kernel B: attention for the 64 window rows ---------------------------
// grid (8 s-groups, 16 heads, 2 batches), 4 waves/block, one (b,h,s) per wave.
__global__ __launch_bounds__(256) void attn_kernel(
    const float* __restrict__ ws, float* __restrict__ Zout) {
  __shared__ float Kn[32 * 64], Kp[32 * 64];     // swizzled
  __shared__ float Vs[32 * XS];
  __shared__ float Pt[4][32 * 36];               // [k][j] pad 36 (float4 j)
  __shared__ float qs[4][64];
  const int tid = threadIdx.x;
  const int wave = tid >> 6, lane = tid & 63;
  const int h = blockIdx.y, b = blockIdx.z;

  // stage K / Kp / V tiles, summing the 8 k-split partials (L2 reads)
  #pragma unroll
  for (int i = 0; i < 8; i++) {
    int e = i * 256 + tid;
    int row = e >> 6, d = e & 63;
    int src = (b * 32 + row) * 1024 + h * 64 + d;
    float kn = 0.f, kp = 0.f, vv = 0.f;
    #pragma unroll
    for (int s = 0; s < NSPLIT; s++) {
      const float* __restrict__ p = ws + (size_t)s * YPART_SZ + src;
      kn += p[65536];        // z=1 K
      kp += p[131072];       // z=2 Kp
      vv += p[196608];       // z=3 V
    }
    Kn[sw_idx(row, d)] = kn;
    Kp[sw_idx(row, d)] = kp;
    Vs[row * XS + d] = vv;
  }
  __syncthreads();

  // l2-normalize K, Kp rows (wave w: rows 8w..8w+7; lane = d)
  for (int rr = 0; rr < 8; rr++) {
    int row = wave * 8 + rr;
    int a = sw_idx(row, lane);
    float kv = Kn[a];
    float s2 = kv * kv;
    #pragma unroll
    for (int off = 1; off < 64; off <<= 1) s2 += __shfl_xor(s2, off);
    Kn[a] = kv * (1.f / (sqrtf(s2) + 1e-7f));
    float pv = Kp[a];
    float p2 = pv * pv;
    #pragma unroll
    for (int off = 1; off < 64; off <<= 1) p2 += __shfl_xor(p2, off);
    Kp[a] = pv * (1.f / (sqrtf(p2) + 1e-7f));
  }
  __syncthreads();

  const int m = blockIdx.x * 4 + wave;   // s_local; valid j,k <= m
  const int r = b * 32 + m;

  // q-hat (lane = d), summing partials
  float q = 0.f;
  {
    int src = r * 1024 + h * 64 + lane;
    #pragma unroll
    for (int s = 0; s < NSPLIT; s++) q += ws[(size_t)s * YPART_SZ + src];
  }
  float q2 = q * q;
  #pragma unroll
  for (int off = 1; off < 64; off <<= 1) q2 += __shfl_xor(q2, off);
  q *= (1.f / (sqrtf(q2) + 1e-7f));
  qs[wave][lane] = q;
  __builtin_amdgcn_wave_barrier();

  // A[j][k] = sum_d qhat[d] Khat[j][d] Kphat[k][d]; 4x4 tile per lane
  const int lj = lane >> 3, lk = lane & 7;
  float acc[4][4];
  #pragma unroll
  for (int a = 0; a < 4; a++)
    #pragma unroll
    for (int c = 0; c < 4; c++) acc[a][c] = 0.f;

  const float* qw = qs[wave];
  for (int dq = 0; dq < 16; dq++) {
    float4 q4 = *(const float4*)(qw + dq * 4);   // broadcast
    const int cj = (((dq + lj) & 15) << 2);      // swizzled quad offset
    const int ck = (((dq + lk) & 15) << 2);
    float4 t4[4], kp4[4];
    #pragma unroll
    for (int tj = 0; tj < 4; tj++) {
      float4 kv = *(const float4*)(Kn + (lj * 4 + tj) * 64 + cj);
      t4[tj].x = q4.x * kv.x; t4[tj].y = q4.y * kv.y;
      t4[tj].z = q4.z * kv.z; t4[tj].w = q4.w * kv.w;
    }
    #pragma unroll
    for (int tk = 0; tk < 4; tk++)
      kp4[tk] = *(const float4*)(Kp + (lk * 4 + tk) * 64 + ck);
    #pragma unroll
    for (int tj = 0; tj < 4; tj++) {
      #pragma unroll
      for (int tk = 0; tk < 4; tk++) {
        // components of t4/kp4 line up on the same (swizzled) d
        acc[tj][tk] += t4[tj].x * kp4[tk].x + t4[tj].y * kp4[tk].y
                     + t4[tj].z * kp4[tk].z + t4[tj].w * kp4[tk].w;
      }
    }
  }

  // masked softmax (scale 1/sqrt(64) = 0.125)
  float amax = -1e30f;
  #pragma unroll
  for (int tj = 0; tj < 4; tj++)
    #pragma unroll
    for (int tk = 0; tk < 4; tk++) {
      int j = lj * 4 + tj, k = lk * 4 + tk;
      if (j <= m && k <= m) amax = fmaxf(amax, acc[tj][tk] * 0.125f);
    }
  #pragma unroll
  for (int off = 1; off < 64; off <<= 1) amax = fmaxf(amax, __shfl_xor(amax, off));

  float lsum = 0.f;
  float* ptw = Pt[wave];
  #pragma unroll
  for (int tk = 0; tk < 4; tk++) {
    int k = lk * 4 + tk;
    float4 ev;
    float* e = (float*)&ev;
    #pragma unroll
    for (int tj = 0; tj < 4; tj++) {
      int j = lj * 4 + tj;
      float x = 0.f;
      if (j <= m && k <= m) x = __expf(acc[tj][tk] * 0.125f - amax);
      e[tj] = x;
      lsum += x;
    }
    *(float4*)(ptw + k * 36 + lj * 4) = ev;      // b128, <=2-way banks
  }
  #pragma unroll
  for (int off = 1; off < 64; off <<= 1) lsum += __shfl_xor(lsum, off);
  float inv = 1.f / lsum;
  __builtin_amdgcn_wave_barrier();

  // Z[d] = sum_k V[k][d] * (sum_j P[j][k] V[j][d]); lane = d
  float vreg[32];
  #pragma unroll
  for (int k = 0; k < 32; k++) vreg[k] = Vs[k * XS + lane];
  float zacc = 0.f;
  for (int k = 0; k <= m; k++) {
    float g0 = 0.f, g1 = 0.f, g2 = 0.f, g3 = 0.f;
    #pragma unroll
    for (int jq = 0; jq < 8; jq++) {
      float4 p = *(const float4*)(ptw + k * 36 + jq * 4);  // b128 broadcast
      g0 = fmaf(p.x, vreg[jq * 4 + 0], g0);
      g1 = fmaf(p.y, vreg[jq * 4 + 1], g1);
      g2 = fmaf(p.z, vreg[jq * 4 + 2], g2);
      g3 = fmaf(p.w, vreg[jq * 4 + 3], g3);
    }
    zacc = fmaf((g0 + g1) + (g2 + g3), vreg[k], zacc);
  }
  Zout[r * 1024 + h * 64 + lane] = zacc * inv;
}

// ---- kernel C: Dpart[ks][64][1024] = Z @ W_O (k-chunk), plain stores ------
// grid (16 colblk, 8 ksplit). Same lane=row + s_load scheme as proj.
__global__ __launch_bounds__(256, 2) void wo_kernel(
    const float* __restrict__ Zr, const float* __restrict__ Wo,
    float* __restrict__ ws) {
  __shared__ float xs[128 * 65];     // [kk][r]
  const int tid = threadIdx.x;
  const int col0 = blockIdx.x * 64;
  const int ks   = blockIdx.y;
  const int k0   = ks * 128;

  #pragma unroll
  for (int i = 0; i < 8; i++) {
    int e = i * 256 + tid;           // 2048 slots: r(64) x quad(32)
    int r = e >> 5, q = e & 31;
    float4 v = *(const float4*)(Zr + r * 1024 + k0 + q * 4);
    xs[(q * 4 + 0) * 65 + r] = v.x;
    xs[(q * 4 + 1) * 65 + r] = v.y;
    xs[(q * 4 + 2) * 65 + r] = v.z;
    xs[(q * 4 + 3) * 65 + r] = v.w;
  }
  __syncthreads();

  const int wave = __builtin_amdgcn_readfirstlane(tid >> 6);
  const int lane = tid & 63;         // = row
  const float* __restrict__ Wt = Wo + (size_t)k0 * 1024 + col0 + wave * 16;

  float acc[16];
  #pragma unroll
  for (int c = 0; c < 16; c++) acc[c] = 0.f;

  #pragma unroll 4
  for (int kk = 0; kk < 128; kk++) {
    float xv = xs[kk * 65 + lane];
    const float* __restrict__ wrow = Wt + kk * 1024;
    #pragma unroll
    for (int c = 0; c < 16; c++) acc[c] = fmaf(xv, wrow[c], acc[c]);
  }

  __syncthreads();
  #pragma unroll
  for (int c = 0; c < 16; c++) xs[lane * 65 + wave * 16 + c] = acc[c];
  __syncthreads();
  float* __restrict__ Do = ws + (size_t)DPART_OFF + (size_t)ks * 65536 + col0;
  #pragma unroll
  for (int i = 0; i < 16; i++) {
    int r = wave * 16 + i;
    Do[r * 1024 + lane] = xs[r * 65 + lane];
  }
}

// ---- kernel D: out = LayerNorm(x + delta), one wave per row ---------------
__global__ __launch_bounds__(256, 4) void ln_kernel(
    const float4* __restrict__ x4, const float4* __restrict__ dpart4,
    const float4* __restrict__ g4, const float4* __restrict__ b4,
    float4* __restrict__ out4) {
  const int tid = threadIdx.x;
  const int wave = tid >> 6, lane = tid & 63;
  const int row = blockIdx.x * 4 + wave;       // 0..4095
  const int b = row >> 11, s = row & 2047;

  float4 v[4];
  #pragma unroll
  for (int i = 0; i < 4; i++) v[i] = x4[row * 256 + i * 64 + lane];
  if (s >= 2016) {                             // wave-uniform branch
    int drow = b * 32 + (s - 2016);
    #pragma unroll
    for (int i = 0; i < 4; i++) {
      #pragma unroll
      for (int sp = 0; sp < NSPLIT; sp++) {
        float4 d = dpart4[sp * 16384 + drow * 256 + i * 64 + lane];
        v[i].x += d.x; v[i].y += d.y; v[i].z += d.z; v[i].w += d.w;
      }
    }
  }
  float sum = 0.f, ss = 0.f;
  #pragma unroll
  for (int i = 0; i < 4; i++) {
    sum += v[i].x + v[i].y + v[i].z + v[i].w;
    ss  += v[i].x * v[i].x + v[i].y * v[i].y + v[i].z * v[i].z + v[i].w * v[i].w;
  }
  #pragma unroll
  for (int off = 1; off < 64; off <<= 1) {
    sum += __shfl_xor(sum, off);
    ss  += __shfl_xor(ss, off);
  }
  float mu   = sum * (1.f / 1024.f);
  float var  = ss * (1.f / 1024.f) - mu * mu;
  float rstd = rsqrtf(var + 1e-5f);

  #pragma unroll
  for (int i = 0; i < 4; i++) {
    float4 g = g4[i * 64 + lane];
    float4 be = b4[i * 64 + lane];
    float4 o;
    o.x = (v[i].x - mu) * rstd * g.x + be.x;
    o.y = (v[i].y - mu) * rstd * g.y + be.y;
    o.z = (v[i].z - mu) * rstd * g.z + be.z;
    o.w = (v[i].w - mu) * rstd * g.w + be.w;
    out4[row * 256 + i * 64 + lane] = o;
  }
}

// ---------------------------------------------------------------------------
extern "C" void kernel_launch(void* const* d_in, const int* in_sizes, int n_in,
                              void* d_out, int out_size, void* d_ws, size_t ws_size,
                              hipStream_t stream) {
  const float* x   = (const float*)d_in[0];
  const float* Wq  = (const float*)d_in[1];
  const float* Wk  = (const float*)d_in[2];
  const float* Wv  = (const float*)d_in[3];  // NB: dict order, W_V before W_Kp
  const float* Wkp = (const float*)d_in[4];
  const float* Wo  = (const float*)d_in[5];
  const float* gam = (const float*)d_in[6];
  const float* bet = (const float*)d_in[7];
  float* out = (float*)d_out;
  float* ws  = (float*)d_ws;   // needs ~10.75 MB

  hipLaunchKernelGGL(proj_kernel, dim3(64, 8), dim3(256), 0, stream,
                     x, Wq, Wk, Wkp, Wv, ws);
  hipLaunchKernelGGL(attn_kernel, dim3(8, 16, 2), dim3(256), 0, stream,
                     ws, ws + Z_OFF);
  hipLaunchKernelGGL(wo_kernel, dim3(16, 8), dim3(256), 0, stream,
                     ws + Z_OFF, Wo, ws);
  hipLaunchKernelGGL(ln_kernel, dim3(1024), dim3(256), 0, stream,
                     (const float4*)x, (const float4*)(ws + DPART_OFF),
                     (const float4*)gam, (const float4*)bet, (float4*)out);
}